// Round 1
// baseline (4540.762 us; speedup 1.0000x reference)
//
#include <hip/hip_runtime.h>
#include <math.h>

#define B_ 4
#define L_ 1024
#define D_ 512
#define E_ 1024
#define R_ 32
#define S_ 16
#define G_ 64
#define NL_ 4

// ---------------- copy x -> out (residual stream init) ----------------
__global__ __launch_bounds__(256)
void copy_kernel(const float* __restrict__ src, float* __restrict__ dst, int n4) {
    int i = blockIdx.x * 256 + threadIdx.x;
    if (i < n4) ((float4*)dst)[i] = ((const float4*)src)[i];
}

// ---------------- layernorm over D=512, one block per token ----------------
__global__ __launch_bounds__(256)
void ln_kernel(const float* __restrict__ x, const float* __restrict__ g,
               const float* __restrict__ b, float* __restrict__ o) {
    int t = blockIdx.x;
    int d = threadIdx.x * 2;
    float2 v = *(const float2*)&x[(size_t)t * D_ + d];
    float s = v.x + v.y;
    float sq = v.x * v.x + v.y * v.y;
#pragma unroll
    for (int m = 1; m < 64; m <<= 1) {
        s += __shfl_xor(s, m);
        sq += __shfl_xor(sq, m);
    }
    __shared__ float ls[4], lq[4];
    int w = threadIdx.x >> 6;
    if ((threadIdx.x & 63) == 0) { ls[w] = s; lq[w] = sq; }
    __syncthreads();
    s = ls[0] + ls[1] + ls[2] + ls[3];
    sq = lq[0] + lq[1] + lq[2] + lq[3];
    float mean = s * (1.0f / D_);
    float var = sq * (1.0f / D_) - mean * mean;
    float rs = rsqrtf(var + 1e-5f);
    float2 gg = *(const float2*)&g[d];
    float2 bb = *(const float2*)&b[d];
    float2 r;
    r.x = (v.x - mean) * rs * gg.x + bb.x;
    r.y = (v.y - mean) * rs * gg.y + bb.y;
    *(float2*)&o[(size_t)t * D_ + d] = r;
}

// ---------------- generic fp32 GEMM: C[M,N] = A[M,K] @ W[N,K]^T ----------------
// 64x64 block tile, BK=32, 256 threads, 4x4 microtile with strided (tx+16j) mapping.
// EPI: 0 = store, 1 = softplus(acc + bias[n]), 2 = accumulate into C.
template <int EPI>
__global__ __launch_bounds__(256)
void gemm_bt(const float* __restrict__ A, int lda,
             const float* __restrict__ W, int ldb,
             float* __restrict__ C, int ldc,
             int K, const float* __restrict__ bias) {
    __shared__ float As[64][36];
    __shared__ float Bs[64][36];
    const int tid = threadIdx.x;
    const int tx = tid & 15, ty = tid >> 4;
    const int m0 = blockIdx.x * 64, n0 = blockIdx.y * 64;
    float acc[4][4] = {};
    for (int k0 = 0; k0 < K; k0 += 32) {
#pragma unroll
        for (int i = 0; i < 2; ++i) {
            int q = tid + i * 256;
            int row = q >> 3, kq = (q & 7) * 4;
            *(float4*)&As[row][kq] = *(const float4*)&A[(size_t)(m0 + row) * lda + k0 + kq];
            *(float4*)&Bs[row][kq] = *(const float4*)&W[(size_t)(n0 + row) * ldb + k0 + kq];
        }
        __syncthreads();
#pragma unroll
        for (int k4 = 0; k4 < 8; ++k4) {
            float4 a4[4], b4[4];
#pragma unroll
            for (int u = 0; u < 4; ++u) {
                a4[u] = *(const float4*)&As[ty + 16 * u][k4 * 4];
                b4[u] = *(const float4*)&Bs[tx + 16 * u][k4 * 4];
            }
#pragma unroll
            for (int i = 0; i < 4; ++i)
#pragma unroll
                for (int j = 0; j < 4; ++j) {
                    acc[i][j] = fmaf(a4[i].x, b4[j].x, acc[i][j]);
                    acc[i][j] = fmaf(a4[i].y, b4[j].y, acc[i][j]);
                    acc[i][j] = fmaf(a4[i].z, b4[j].z, acc[i][j]);
                    acc[i][j] = fmaf(a4[i].w, b4[j].w, acc[i][j]);
                }
        }
        __syncthreads();
    }
#pragma unroll
    for (int i = 0; i < 4; ++i) {
        int m = m0 + ty + 16 * i;
#pragma unroll
        for (int j = 0; j < 4; ++j) {
            int n = n0 + tx + 16 * j;
            float v = acc[i][j];
            if (EPI == 1) {
                v += bias[n];
                v = fmaxf(v, 0.f) + log1pf(expf(-fabsf(v)));  // stable softplus
            } else if (EPI == 2) {
                v += C[(size_t)m * ldc + n];
            }
            C[(size_t)m * ldc + n] = v;
        }
    }
}

// ---------------- depthwise causal conv (D_CONV=4) + SiLU ----------------
// reads xc half of xz (row stride 2E), writes xcs (row stride E)
__global__ __launch_bounds__(256)
void conv_silu(const float* __restrict__ xz, const float* __restrict__ cw,
               const float* __restrict__ cb, float* __restrict__ xcs) {
    int idx = blockIdx.x * 256 + threadIdx.x;  // over B*L*E
    int d = idx & (E_ - 1);
    int bl = idx >> 10;
    int l = bl & (L_ - 1);
    float4 w = *(const float4*)&cw[d * 4];
    float s = cb[d];
    const float* p = xz + (size_t)bl * 2 * E_ + d;
    if (l >= 3) s += p[-3 * 2 * E_] * w.x;
    if (l >= 2) s += p[-2 * 2 * E_] * w.y;
    if (l >= 1) s += p[-1 * 2 * E_] * w.z;
    s += p[0] * w.w;
    xcs[idx] = s / (1.0f + expf(-s));  // silu
}

// ---------------- selective scan ----------------
// one thread per (b, d, s); 16-lane shfl reduce over s; fused Dp*xc + silu(z) gate.
// y written into the (dead) xc half of xz, row stride 2E.
__global__ __launch_bounds__(256)
void scan_kernel(const float* __restrict__ dt, const float* __restrict__ xcs,
                 const float* __restrict__ dbl, const float* __restrict__ xzin,
                 const float* __restrict__ A_log, const float* __restrict__ Dp,
                 float* __restrict__ yout) {
    int b = blockIdx.x >> 6;
    int dc = blockIdx.x & 63;
    int s = threadIdx.x & 15;
    int dl = threadIdx.x >> 4;
    int d = dc * 16 + dl;
    float A = -expf(A_log[d * S_ + s]);
    float Dpd = Dp[d];
    float h = 0.f;
    const size_t tb = (size_t)b * L_;
    for (int l = 0; l < L_; ++l) {
        size_t t = tb + l;
        float dtv = dt[t * E_ + d];
        float xc = xcs[t * E_ + d];
        float Bv = dbl[t * G_ + R_ + s];
        float Cv = dbl[t * G_ + R_ + S_ + s];
        float dA = expf(dtv * A);
        h = fmaf(dA, h, dtv * Bv * xc);
        float p = h * Cv;
        p += __shfl_xor(p, 1);
        p += __shfl_xor(p, 2);
        p += __shfl_xor(p, 4);
        p += __shfl_xor(p, 8);
        if (s == 0) {
            float z = xzin[t * 2 * E_ + E_ + d];
            float sz = z / (1.0f + expf(-z));
            yout[t * 2 * E_ + d] = (p + Dpd * xc) * sz;
        }
    }
}

extern "C" void kernel_launch(void* const* d_in, const int* in_sizes, int n_in,
                              void* d_out, int out_size, void* d_ws, size_t ws_size,
                              hipStream_t stream) {
    const float* x = (const float*)d_in[0];
    const float* ln_g = (const float*)d_in[1];
    const float* ln_b = (const float*)d_in[2];
    const float* in_w = (const float*)d_in[3];
    const float* cw = (const float*)d_in[4];
    const float* cb = (const float*)d_in[5];
    const float* xp_w = (const float*)d_in[6];
    const float* dt_w = (const float*)d_in[7];
    const float* dt_b = (const float*)d_in[8];
    const float* A_log = (const float*)d_in[9];
    const float* Dp = (const float*)d_in[10];
    const float* out_w = (const float*)d_in[11];
    float* out = (float*)d_out;

    float* ws = (float*)d_ws;
    float* xn = ws;                                // B*L*D   =  2M floats
    float* xz = xn + (size_t)B_ * L_ * D_;         // B*L*2E  =  8M floats
    float* xcs = xz + (size_t)B_ * L_ * 2 * E_;    // B*L*E   =  4M floats
    float* dbl = xcs + (size_t)B_ * L_ * E_;       // B*L*G   =  0.25M floats
    float* dt = dbl + (size_t)B_ * L_ * G_;        // B*L*E   =  4M floats

    // residual stream lives in d_out
    copy_kernel<<<(B_ * L_ * D_ / 4 + 255) / 256, 256, 0, stream>>>(x, out, B_ * L_ * D_ / 4);

    for (int i = 0; i < NL_; ++i) {
        ln_kernel<<<B_ * L_, 256, 0, stream>>>(out, ln_g + i * D_, ln_b + i * D_, xn);
        // xz = xn @ in_w^T : M=4096, N=2048, K=512
        gemm_bt<0><<<dim3(64, 32), 256, 0, stream>>>(
            xn, D_, in_w + (size_t)i * 2 * E_ * D_, D_, xz, 2 * E_, D_, nullptr);
        conv_silu<<<(B_ * L_ * E_) / 256, 256, 0, stream>>>(
            xz, cw + i * E_ * 4, cb + i * E_, xcs);
        // dbl = xcs @ xp_w^T : M=4096, N=64, K=1024
        gemm_bt<0><<<dim3(64, 1), 256, 0, stream>>>(
            xcs, E_, xp_w + (size_t)i * G_ * E_, E_, dbl, G_, E_, nullptr);
        // dt = softplus(dbl[:, :32] @ dt_w^T + dt_b) : M=4096, N=1024, K=32
        gemm_bt<1><<<dim3(64, 16), 256, 0, stream>>>(
            dbl, G_, dt_w + (size_t)i * E_ * R_, R_, dt, E_, R_, dt_b + i * E_);
        // scan + gate; y -> xc half of xz (stride 2E)
        scan_kernel<<<B_ * 64, 256, 0, stream>>>(
            dt, xcs, dbl, xz, A_log + (size_t)i * E_ * S_, Dp + i * E_, xz);
        // out += y @ out_w^T : M=4096, N=512, K=1024
        gemm_bt<2><<<dim3(64, 8), 256, 0, stream>>>(
            xz, 2 * E_, out_w + (size_t)i * D_ * E_, E_, out, D_, E_, nullptr);
    }
}

// Round 2
// 1952.893 us; speedup vs baseline: 2.3251x; 2.3251x over previous
//
#include <hip/hip_runtime.h>
#include <math.h>

#define B_ 4
#define L_ 1024
#define D_ 512
#define E_ 1024
#define R_ 32
#define S_ 16
#define G_ 64
#define NL_ 4
#define NC_ 32   // chunks over L
#define CT_ 32   // chunk length (NC_*CT_ == L_)
#define SUM_ (B_ * E_ * S_)  // 65536 summaries per chunk

// ---------------- copy x -> out (residual stream init) ----------------
__global__ __launch_bounds__(256)
void copy_kernel(const float* __restrict__ src, float* __restrict__ dst, int n4) {
    int i = blockIdx.x * 256 + threadIdx.x;
    if (i < n4) ((float4*)dst)[i] = ((const float4*)src)[i];
}

// ---------------- layernorm over D=512, one block per token ----------------
__global__ __launch_bounds__(256)
void ln_kernel(const float* __restrict__ x, const float* __restrict__ g,
               const float* __restrict__ b, float* __restrict__ o) {
    int t = blockIdx.x;
    int d = threadIdx.x * 2;
    float2 v = *(const float2*)&x[(size_t)t * D_ + d];
    float s = v.x + v.y;
    float sq = v.x * v.x + v.y * v.y;
#pragma unroll
    for (int m = 1; m < 64; m <<= 1) {
        s += __shfl_xor(s, m);
        sq += __shfl_xor(sq, m);
    }
    __shared__ float ls[4], lq[4];
    int w = threadIdx.x >> 6;
    if ((threadIdx.x & 63) == 0) { ls[w] = s; lq[w] = sq; }
    __syncthreads();
    s = ls[0] + ls[1] + ls[2] + ls[3];
    sq = lq[0] + lq[1] + lq[2] + lq[3];
    float mean = s * (1.0f / D_);
    float var = sq * (1.0f / D_) - mean * mean;
    float rs = rsqrtf(var + 1e-5f);
    float2 gg = *(const float2*)&g[d];
    float2 bb = *(const float2*)&b[d];
    float2 r;
    r.x = (v.x - mean) * rs * gg.x + bb.x;
    r.y = (v.y - mean) * rs * gg.y + bb.y;
    *(float2*)&o[(size_t)t * D_ + d] = r;
}

// ---------------- generic fp32 GEMM: C[M,N] = A[M,K] @ W[N,K]^T ----------------
template <int EPI>
__global__ __launch_bounds__(256)
void gemm_bt(const float* __restrict__ A, int lda,
             const float* __restrict__ W, int ldb,
             float* __restrict__ C, int ldc,
             int K, const float* __restrict__ bias) {
    __shared__ float As[64][36];
    __shared__ float Bs[64][36];
    const int tid = threadIdx.x;
    const int tx = tid & 15, ty = tid >> 4;
    const int m0 = blockIdx.x * 64, n0 = blockIdx.y * 64;
    float acc[4][4] = {};
    for (int k0 = 0; k0 < K; k0 += 32) {
#pragma unroll
        for (int i = 0; i < 2; ++i) {
            int q = tid + i * 256;
            int row = q >> 3, kq = (q & 7) * 4;
            *(float4*)&As[row][kq] = *(const float4*)&A[(size_t)(m0 + row) * lda + k0 + kq];
            *(float4*)&Bs[row][kq] = *(const float4*)&W[(size_t)(n0 + row) * ldb + k0 + kq];
        }
        __syncthreads();
#pragma unroll
        for (int k4 = 0; k4 < 8; ++k4) {
            float4 a4[4], b4[4];
#pragma unroll
            for (int u = 0; u < 4; ++u) {
                a4[u] = *(const float4*)&As[ty + 16 * u][k4 * 4];
                b4[u] = *(const float4*)&Bs[tx + 16 * u][k4 * 4];
            }
#pragma unroll
            for (int i = 0; i < 4; ++i)
#pragma unroll
                for (int j = 0; j < 4; ++j) {
                    acc[i][j] = fmaf(a4[i].x, b4[j].x, acc[i][j]);
                    acc[i][j] = fmaf(a4[i].y, b4[j].y, acc[i][j]);
                    acc[i][j] = fmaf(a4[i].z, b4[j].z, acc[i][j]);
                    acc[i][j] = fmaf(a4[i].w, b4[j].w, acc[i][j]);
                }
        }
        __syncthreads();
    }
#pragma unroll
    for (int i = 0; i < 4; ++i) {
        int m = m0 + ty + 16 * i;
#pragma unroll
        for (int j = 0; j < 4; ++j) {
            int n = n0 + tx + 16 * j;
            float v = acc[i][j];
            if (EPI == 1) {
                v += bias[n];
                v = fmaxf(v, 0.f) + log1pf(expf(-fabsf(v)));  // stable softplus
            } else if (EPI == 2) {
                v += C[(size_t)m * ldc + n];
            }
            C[(size_t)m * ldc + n] = v;
        }
    }
}

// ---------------- depthwise causal conv (D_CONV=4) + SiLU ----------------
__global__ __launch_bounds__(256)
void conv_silu(const float* __restrict__ xz, const float* __restrict__ cw,
               const float* __restrict__ cb, float* __restrict__ xcs) {
    int idx = blockIdx.x * 256 + threadIdx.x;  // over B*L*E
    int d = idx & (E_ - 1);
    int bl = idx >> 10;
    int l = bl & (L_ - 1);
    float4 w = *(const float4*)&cw[d * 4];
    float s = cb[d];
    const float* p = xz + (size_t)bl * 2 * E_ + d;
    if (l >= 3) s += p[-3 * 2 * E_] * w.x;
    if (l >= 2) s += p[-2 * 2 * E_] * w.y;
    if (l >= 1) s += p[-1 * 2 * E_] * w.z;
    s += p[0] * w.w;
    xcs[idx] = s / (1.0f + expf(-s));  // silu
}

// ---------------- chunked selective scan ----------------
// Recurrence h_t = dA_t*h + u_t split into NC_ chunks of CT_ steps.
// Pass 1: per (b,d,s,chunk) compute P=prod(dA), Q=fold(u). 8192 blocks -> full occupancy.
__global__ __launch_bounds__(256)
void scan_pass1(const float* __restrict__ dt, const float* __restrict__ xcs,
                const float* __restrict__ dbl, const float* __restrict__ A_log,
                float* __restrict__ asum, float* __restrict__ bsum) {
    int c = blockIdx.x & (NC_ - 1);
    int dg = (blockIdx.x >> 5) & 63;
    int b = blockIdx.x >> 11;
    int s = threadIdx.x & 15;
    int dl = threadIdx.x >> 4;
    int d = dg * 16 + dl;
    float A = -expf(A_log[d * S_ + s]);
    float P = 1.f, Q = 0.f;
    const size_t tb = (size_t)b * L_ + c * CT_;
#pragma unroll 4
    for (int l = 0; l < CT_; ++l) {
        size_t t = tb + l;
        float dtv = dt[t * E_ + d];
        float xc = xcs[t * E_ + d];
        float Bv = dbl[t * G_ + R_ + s];
        float dA = expf(dtv * A);
        P *= dA;
        Q = fmaf(dA, Q, dtv * Bv * xc);
    }
    int idx = c * SUM_ + b * (E_ * S_) + d * S_ + s;
    asum[idx] = P;
    bsum[idx] = Q;
}

// Pass 2: per (b,d,s) scan the NC_ chunk summaries; asum becomes h0 (chunk-entry state).
// Same-thread read-before-write makes the aliasing safe.
__global__ __launch_bounds__(256)
void scan_pass2(float* __restrict__ asum, const float* __restrict__ bsum) {
    int i = blockIdx.x * 256 + threadIdx.x;  // SUM_ threads
    float h = 0.f;
#pragma unroll
    for (int c = 0; c < NC_; ++c) {
        int idx = c * SUM_ + i;
        float a = asum[idx];
        float q = bsum[idx];
        asum[idx] = h;  // h at chunk entry
        h = fmaf(a, h, q);
    }
}

// Pass 3: per (b,d,s,chunk) rerun recurrence from h0 (bit-identical to sequential),
// reduce h*C over s, apply Dp*xc + silu(z), write y into xc half of xz.
__global__ __launch_bounds__(256)
void scan_pass3(const float* __restrict__ dt, const float* __restrict__ xcs,
                const float* __restrict__ dbl, const float* __restrict__ xzin,
                const float* __restrict__ A_log, const float* __restrict__ Dp,
                const float* __restrict__ h0, float* __restrict__ yout) {
    int c = blockIdx.x & (NC_ - 1);
    int dg = (blockIdx.x >> 5) & 63;
    int b = blockIdx.x >> 11;
    int s = threadIdx.x & 15;
    int dl = threadIdx.x >> 4;
    int d = dg * 16 + dl;
    float A = -expf(A_log[d * S_ + s]);
    float Dpd = Dp[d];
    float h = h0[c * SUM_ + b * (E_ * S_) + d * S_ + s];
    const size_t tb = (size_t)b * L_ + c * CT_;
#pragma unroll 4
    for (int l = 0; l < CT_; ++l) {
        size_t t = tb + l;
        float dtv = dt[t * E_ + d];
        float xc = xcs[t * E_ + d];
        float Bv = dbl[t * G_ + R_ + s];
        float Cv = dbl[t * G_ + R_ + S_ + s];
        float dA = expf(dtv * A);
        h = fmaf(dA, h, dtv * Bv * xc);
        float p = h * Cv;
        p += __shfl_xor(p, 1);
        p += __shfl_xor(p, 2);
        p += __shfl_xor(p, 4);
        p += __shfl_xor(p, 8);
        if (s == 0) {
            float z = xzin[t * 2 * E_ + E_ + d];
            float sz = z / (1.0f + expf(-z));
            yout[t * 2 * E_ + d] = (p + Dpd * xc) * sz;
        }
    }
}

extern "C" void kernel_launch(void* const* d_in, const int* in_sizes, int n_in,
                              void* d_out, int out_size, void* d_ws, size_t ws_size,
                              hipStream_t stream) {
    const float* x = (const float*)d_in[0];
    const float* ln_g = (const float*)d_in[1];
    const float* ln_b = (const float*)d_in[2];
    const float* in_w = (const float*)d_in[3];
    const float* cw = (const float*)d_in[4];
    const float* cb = (const float*)d_in[5];
    const float* xp_w = (const float*)d_in[6];
    const float* dt_w = (const float*)d_in[7];
    const float* dt_b = (const float*)d_in[8];
    const float* A_log = (const float*)d_in[9];
    const float* Dp = (const float*)d_in[10];
    const float* out_w = (const float*)d_in[11];
    float* out = (float*)d_out;

    float* ws = (float*)d_ws;
    float* xn = ws;                                 // B*L*D   =  2M floats
    float* xz = xn + (size_t)B_ * L_ * D_;          // B*L*2E  =  8M floats
    float* xcs = xz + (size_t)B_ * L_ * 2 * E_;     // B*L*E   =  4M floats
    float* dbl = xcs + (size_t)B_ * L_ * E_;        // B*L*G   = .25M floats
    float* dt = dbl + (size_t)B_ * L_ * G_;         // B*L*E   =  4M floats
    float* asum = dt + (size_t)B_ * L_ * E_;        // NC*SUM  =  2M floats (becomes h0)
    float* bsum = asum + (size_t)NC_ * SUM_;        // NC*SUM  =  2M floats

    // residual stream lives in d_out
    copy_kernel<<<(B_ * L_ * D_ / 4 + 255) / 256, 256, 0, stream>>>(x, out, B_ * L_ * D_ / 4);

    for (int i = 0; i < NL_; ++i) {
        ln_kernel<<<B_ * L_, 256, 0, stream>>>(out, ln_g + i * D_, ln_b + i * D_, xn);
        // xz = xn @ in_w^T : M=4096, N=2048, K=512
        gemm_bt<0><<<dim3(64, 32), 256, 0, stream>>>(
            xn, D_, in_w + (size_t)i * 2 * E_ * D_, D_, xz, 2 * E_, D_, nullptr);
        conv_silu<<<(B_ * L_ * E_) / 256, 256, 0, stream>>>(
            xz, cw + i * E_ * 4, cb + i * E_, xcs);
        // dbl = xcs @ xp_w^T : M=4096, N=64, K=1024
        gemm_bt<0><<<dim3(64, 1), 256, 0, stream>>>(
            xcs, E_, xp_w + (size_t)i * G_ * E_, E_, dbl, G_, E_, nullptr);
        // dt = softplus(dbl[:, :32] @ dt_w^T + dt_b) : M=4096, N=1024, K=32
        gemm_bt<1><<<dim3(64, 16), 256, 0, stream>>>(
            dbl, G_, dt_w + (size_t)i * E_ * R_, R_, dt, E_, R_, dt_b + i * E_);
        // chunked scan
        scan_pass1<<<B_ * 64 * NC_, 256, 0, stream>>>(
            dt, xcs, dbl, A_log + (size_t)i * E_ * S_, asum, bsum);
        scan_pass2<<<SUM_ / 256, 256, 0, stream>>>(asum, bsum);
        scan_pass3<<<B_ * 64 * NC_, 256, 0, stream>>>(
            dt, xcs, dbl, xz, A_log + (size_t)i * E_ * S_, Dp + i * E_, asum, xz);
        // out += y @ out_w^T : M=4096, N=512, K=1024
        gemm_bt<2><<<dim3(64, 8), 256, 0, stream>>>(
            xz, 2 * E_, out_w + (size_t)i * D_ * E_, E_, out, D_, E_, nullptr);
    }
}

// Round 3
// 1128.440 us; speedup vs baseline: 4.0239x; 1.7306x over previous
//
#include <hip/hip_runtime.h>
#include <math.h>

#define B_ 4
#define L_ 1024
#define D_ 512
#define E_ 1024
#define R_ 32
#define S_ 16
#define G_ 64
#define NL_ 4
#define NC_ 32   // chunks over L
#define CT_ 32   // chunk length
#define SUM_ (B_ * E_ * S_)

typedef __attribute__((ext_vector_type(8))) short bf16x8;
typedef __attribute__((ext_vector_type(4))) float f32x4;

__device__ __forceinline__ unsigned short f2bf(float f) {
    unsigned u = __float_as_uint(f);
    u += 0x7fff + ((u >> 16) & 1);   // RNE
    return (unsigned short)(u >> 16);
}
__device__ __forceinline__ float bf2f(unsigned short h) {
    return __uint_as_float((unsigned)h << 16);
}

__device__ __forceinline__ void gload16(const void* g, void* l) {
    __builtin_amdgcn_global_load_lds(
        (const __attribute__((address_space(1))) unsigned int*)g,
        (__attribute__((address_space(3))) unsigned int*)l, 16, 0, 0);
}

// ---------------- copy x -> out (residual stream init) ----------------
__global__ __launch_bounds__(256)
void copy_kernel(const float* __restrict__ src, float* __restrict__ dst, int n4) {
    int i = blockIdx.x * 256 + threadIdx.x;
    if (i < n4) ((float4*)dst)[i] = ((const float4*)src)[i];
}

// ---------------- fp32 -> bf16 bulk convert (weights) ----------------
__global__ __launch_bounds__(256)
void cvt_bf16(const float* __restrict__ src, unsigned short* __restrict__ dst, int n4) {
    int i = blockIdx.x * 256 + threadIdx.x;
    if (i < n4) {
        float4 v = ((const float4*)src)[i];
        ushort4 o;
        o.x = f2bf(v.x); o.y = f2bf(v.y); o.z = f2bf(v.z); o.w = f2bf(v.w);
        ((ushort4*)dst)[i] = o;
    }
}

// ---------------- layernorm over D=512, one block per token, bf16 out ----------------
__global__ __launch_bounds__(256)
void ln_kernel(const float* __restrict__ x, const float* __restrict__ g,
               const float* __restrict__ b, unsigned short* __restrict__ o) {
    int t = blockIdx.x;
    int d = threadIdx.x * 2;
    float2 v = *(const float2*)&x[(size_t)t * D_ + d];
    float s = v.x + v.y;
    float sq = v.x * v.x + v.y * v.y;
#pragma unroll
    for (int m = 1; m < 64; m <<= 1) {
        s += __shfl_xor(s, m);
        sq += __shfl_xor(sq, m);
    }
    __shared__ float ls[4], lq[4];
    int w = threadIdx.x >> 6;
    if ((threadIdx.x & 63) == 0) { ls[w] = s; lq[w] = sq; }
    __syncthreads();
    s = ls[0] + ls[1] + ls[2] + ls[3];
    sq = lq[0] + lq[1] + lq[2] + lq[3];
    float mean = s * (1.0f / D_);
    float var = sq * (1.0f / D_) - mean * mean;
    float rs = rsqrtf(var + 1e-5f);
    float2 gg = *(const float2*)&g[d];
    float2 bb = *(const float2*)&b[d];
    ushort2 r;
    r.x = f2bf((v.x - mean) * rs * gg.x + bb.x);
    r.y = f2bf((v.y - mean) * rs * gg.y + bb.y);
    *(ushort2*)&o[(size_t)t * D_ + d] = r;
}

// ---------------- bf16 MFMA GEMM: C[M,N] = A[M,K] @ W[N,K]^T ----------------
// m97 structure: global_load_lds(16B) staging, 16x16x32 MFMA.
// EPI: 0 = store fp32, 1 = store bf16, 2 = accumulate fp32.
template <int BM, int BN, int WM, int WN, int EPI>
__global__ __launch_bounds__(256)
void gemm_mfma(const unsigned short* __restrict__ A, int lda,
               const unsigned short* __restrict__ W, int ldb,
               void* __restrict__ Cv, int ldc, int K) {
    constexpr int IA = BM / 64;  // staging issues (256 thr * 16B = 64 rows of 32 bf16)
    constexpr int IB = BN / 64;
    constexpr int NWN = BN / WN;
    constexpr int MI = WM / 16, NJ = WN / 16;
    __shared__ unsigned short As[BM * 32];
    __shared__ unsigned short Bs[BN * 32];
    const int tid = threadIdx.x;
    const int wave = tid >> 6, lane = tid & 63;
    const int quad = lane >> 4, r = lane & 15;
    const int wm = (wave / NWN) * WM, wn = (wave % NWN) * WN;
    const int m0 = blockIdx.x * BM, n0 = blockIdx.y * BN;
    const int arow = tid >> 2, acol = (tid & 3) * 8;
    const unsigned short* Ag = A + (size_t)(m0 + arow) * lda + acol;
    const unsigned short* Wg = W + (size_t)(n0 + arow) * ldb + acol;
    f32x4 acc[MI][NJ] = {};
    for (int k0 = 0; k0 < K; k0 += 32) {
        __syncthreads();
#pragma unroll
        for (int q = 0; q < IA; ++q)
            gload16(Ag + (size_t)(64 * q) * lda + k0, &As[(q * 256 + tid) * 8]);
#pragma unroll
        for (int q = 0; q < IB; ++q)
            gload16(Wg + (size_t)(64 * q) * ldb + k0, &Bs[(q * 256 + tid) * 8]);
        __syncthreads();
        bf16x8 af[MI], bfr[NJ];
#pragma unroll
        for (int i = 0; i < MI; ++i)
            af[i] = *(const bf16x8*)&As[(wm + i * 16 + r) * 32 + quad * 8];
#pragma unroll
        for (int j = 0; j < NJ; ++j)
            bfr[j] = *(const bf16x8*)&Bs[(wn + j * 16 + r) * 32 + quad * 8];
#pragma unroll
        for (int i = 0; i < MI; ++i)
#pragma unroll
            for (int j = 0; j < NJ; ++j)
                acc[i][j] = __builtin_amdgcn_mfma_f32_16x16x32_bf16(af[i], bfr[j], acc[i][j], 0, 0, 0);
    }
#pragma unroll
    for (int i = 0; i < MI; ++i) {
        int mrow = m0 + wm + i * 16 + quad * 4;
#pragma unroll
        for (int j = 0; j < NJ; ++j) {
            int n = n0 + wn + j * 16 + r;
#pragma unroll
            for (int t = 0; t < 4; ++t) {
                float v = acc[i][j][t];
                size_t off = (size_t)(mrow + t) * ldc + n;
                if (EPI == 1) {
                    ((unsigned short*)Cv)[off] = f2bf(v);
                } else if (EPI == 2) {
                    float* C = (float*)Cv;
                    C[off] = v + C[off];
                } else {
                    ((float*)Cv)[off] = v;
                }
            }
        }
    }
}

// ---------------- fp32 vector GEMM (dt_proj only, K=32): softplus epilogue ----------------
__global__ __launch_bounds__(256)
void gemm_dt(const float* __restrict__ A, int lda,
             const float* __restrict__ W, int ldb,
             float* __restrict__ C, int ldc,
             int K, const float* __restrict__ bias) {
    __shared__ float As[64][36];
    __shared__ float Bs[64][36];
    const int tid = threadIdx.x;
    const int tx = tid & 15, ty = tid >> 4;
    const int m0 = blockIdx.x * 64, n0 = blockIdx.y * 64;
    float acc[4][4] = {};
    for (int k0 = 0; k0 < K; k0 += 32) {
#pragma unroll
        for (int i = 0; i < 2; ++i) {
            int q = tid + i * 256;
            int row = q >> 3, kq = (q & 7) * 4;
            *(float4*)&As[row][kq] = *(const float4*)&A[(size_t)(m0 + row) * lda + k0 + kq];
            *(float4*)&Bs[row][kq] = *(const float4*)&W[(size_t)(n0 + row) * ldb + k0 + kq];
        }
        __syncthreads();
#pragma unroll
        for (int k4 = 0; k4 < 8; ++k4) {
            float4 a4[4], b4[4];
#pragma unroll
            for (int u = 0; u < 4; ++u) {
                a4[u] = *(const float4*)&As[ty + 16 * u][k4 * 4];
                b4[u] = *(const float4*)&Bs[tx + 16 * u][k4 * 4];
            }
#pragma unroll
            for (int i = 0; i < 4; ++i)
#pragma unroll
                for (int j = 0; j < 4; ++j) {
                    acc[i][j] = fmaf(a4[i].x, b4[j].x, acc[i][j]);
                    acc[i][j] = fmaf(a4[i].y, b4[j].y, acc[i][j]);
                    acc[i][j] = fmaf(a4[i].z, b4[j].z, acc[i][j]);
                    acc[i][j] = fmaf(a4[i].w, b4[j].w, acc[i][j]);
                }
        }
        __syncthreads();
    }
#pragma unroll
    for (int i = 0; i < 4; ++i) {
        int m = m0 + ty + 16 * i;
#pragma unroll
        for (int j = 0; j < 4; ++j) {
            int n = n0 + tx + 16 * j;
            float v = acc[i][j] + bias[n];
            v = fmaxf(v, 0.f) + log1pf(expf(-fabsf(v)));  // stable softplus
            C[(size_t)m * ldc + n] = v;
        }
    }
}

// ---------------- depthwise causal conv (D_CONV=4) + SiLU, bf16 in/out ----------------
__global__ __launch_bounds__(256)
void conv_silu(const unsigned short* __restrict__ xz, const float* __restrict__ cw,
               const float* __restrict__ cb, unsigned short* __restrict__ xcs) {
    int idx = blockIdx.x * 256 + threadIdx.x;  // over B*L*E
    int d = idx & (E_ - 1);
    int bl = idx >> 10;
    int l = bl & (L_ - 1);
    float4 w = *(const float4*)&cw[d * 4];
    float s = cb[d];
    const unsigned short* p = xz + (size_t)bl * 2 * E_ + d;
    if (l >= 3) s += bf2f(p[-3 * 2 * E_]) * w.x;
    if (l >= 2) s += bf2f(p[-2 * 2 * E_]) * w.y;
    if (l >= 1) s += bf2f(p[-1 * 2 * E_]) * w.z;
    s += bf2f(p[0]) * w.w;
    xcs[idx] = f2bf(s / (1.0f + expf(-s)));
}

// ---------------- chunked selective scan ----------------
__global__ __launch_bounds__(256)
void scan_pass1(const float* __restrict__ dt, const unsigned short* __restrict__ xcs,
                const float* __restrict__ dbl, const float* __restrict__ A_log,
                float* __restrict__ asum, float* __restrict__ bsum) {
    int c = blockIdx.x & (NC_ - 1);
    int dg = (blockIdx.x >> 5) & 63;
    int b = blockIdx.x >> 11;
    int s = threadIdx.x & 15;
    int dl = threadIdx.x >> 4;
    int d = dg * 16 + dl;
    float A = -expf(A_log[d * S_ + s]);
    float P = 1.f, Q = 0.f;
    const size_t tb = (size_t)b * L_ + c * CT_;
#pragma unroll 4
    for (int l = 0; l < CT_; ++l) {
        size_t t = tb + l;
        float dtv = dt[t * E_ + d];
        float xc = bf2f(xcs[t * E_ + d]);
        float Bv = dbl[t * G_ + R_ + s];
        float dA = expf(dtv * A);
        P *= dA;
        Q = fmaf(dA, Q, dtv * Bv * xc);
    }
    int idx = c * SUM_ + b * (E_ * S_) + d * S_ + s;
    asum[idx] = P;
    bsum[idx] = Q;
}

__global__ __launch_bounds__(256)
void scan_pass2(float* __restrict__ asum, const float* __restrict__ bsum) {
    int i = blockIdx.x * 256 + threadIdx.x;
    float h = 0.f;
#pragma unroll
    for (int c = 0; c < NC_; ++c) {
        int idx = c * SUM_ + i;
        float a = asum[idx];
        float q = bsum[idx];
        asum[idx] = h;  // h at chunk entry
        h = fmaf(a, h, q);
    }
}

__global__ __launch_bounds__(256)
void scan_pass3(const float* __restrict__ dt, const unsigned short* __restrict__ xcs,
                const float* __restrict__ dbl, const unsigned short* __restrict__ xzin,
                const float* __restrict__ A_log, const float* __restrict__ Dp,
                const float* __restrict__ h0, unsigned short* __restrict__ ybf) {
    int c = blockIdx.x & (NC_ - 1);
    int dg = (blockIdx.x >> 5) & 63;
    int b = blockIdx.x >> 11;
    int s = threadIdx.x & 15;
    int dl = threadIdx.x >> 4;
    int d = dg * 16 + dl;
    float A = -expf(A_log[d * S_ + s]);
    float Dpd = Dp[d];
    float h = h0[c * SUM_ + b * (E_ * S_) + d * S_ + s];
    const size_t tb = (size_t)b * L_ + c * CT_;
#pragma unroll 4
    for (int l = 0; l < CT_; ++l) {
        size_t t = tb + l;
        float dtv = dt[t * E_ + d];
        float xc = bf2f(xcs[t * E_ + d]);
        float Bv = dbl[t * G_ + R_ + s];
        float Cv = dbl[t * G_ + R_ + S_ + s];
        float dA = expf(dtv * A);
        h = fmaf(dA, h, dtv * Bv * xc);
        float p = h * Cv;
        p += __shfl_xor(p, 1);
        p += __shfl_xor(p, 2);
        p += __shfl_xor(p, 4);
        p += __shfl_xor(p, 8);
        if (s == 0) {
            float z = bf2f(xzin[t * 2 * E_ + E_ + d]);
            float sz = z / (1.0f + expf(-z));
            ybf[t * E_ + d] = f2bf((p + Dpd * xc) * sz);
        }
    }
}

extern "C" void kernel_launch(void* const* d_in, const int* in_sizes, int n_in,
                              void* d_out, int out_size, void* d_ws, size_t ws_size,
                              hipStream_t stream) {
    const float* x = (const float*)d_in[0];
    const float* ln_g = (const float*)d_in[1];
    const float* ln_b = (const float*)d_in[2];
    const float* in_w = (const float*)d_in[3];
    const float* cw = (const float*)d_in[4];
    const float* cb = (const float*)d_in[5];
    const float* xp_w = (const float*)d_in[6];
    const float* dt_w = (const float*)d_in[7];
    const float* dt_b = (const float*)d_in[8];
    const float* A_log = (const float*)d_in[9];
    const float* Dp = (const float*)d_in[10];
    const float* out_w = (const float*)d_in[11];
    float* out = (float*)d_out;

    // ---- workspace layout (78 MB) ----
    char* p = (char*)d_ws;
    unsigned short* xz = (unsigned short*)p;        p += (size_t)B_ * L_ * 2 * E_ * 2;  // 16 MB bf16
    unsigned short* xcs = (unsigned short*)p;       p += (size_t)B_ * L_ * E_ * 2;      // 8 MB
    float* dbl = (float*)p;                         p += (size_t)B_ * L_ * G_ * 4;      // 1 MB
    float* dt = (float*)p;                          p += (size_t)B_ * L_ * E_ * 4;      // 16 MB
    float* asum = (float*)p;                        p += (size_t)NC_ * SUM_ * 4;        // 8 MB
    float* bsum = (float*)p;                        p += (size_t)NC_ * SUM_ * 4;        // 8 MB
    unsigned short* ybf = (unsigned short*)p;       // 8 MB region, aliased:
    unsigned short* xnbf = (unsigned short*)p;      //   xnbf live ln->in_proj; ybf live pass3->out_proj
    p += (size_t)B_ * L_ * E_ * 2;
    unsigned short* in_w_bf = (unsigned short*)p;   p += (size_t)NL_ * 2 * E_ * D_ * 2; // 8.4 MB
    unsigned short* xp_w_bf = (unsigned short*)p;   p += (size_t)NL_ * G_ * E_ * 2;     // 0.5 MB
    unsigned short* out_w_bf = (unsigned short*)p;  // 4.2 MB

    // residual stream lives in d_out
    copy_kernel<<<(B_ * L_ * D_ / 4 + 255) / 256, 256, 0, stream>>>(x, out, B_ * L_ * D_ / 4);
    // weights -> bf16 (once per call)
    cvt_bf16<<<(NL_ * 2 * E_ * D_ / 4 + 255) / 256, 256, 0, stream>>>(in_w, in_w_bf, NL_ * 2 * E_ * D_ / 4);
    cvt_bf16<<<(NL_ * G_ * E_ / 4 + 255) / 256, 256, 0, stream>>>(xp_w, xp_w_bf, NL_ * G_ * E_ / 4);
    cvt_bf16<<<(NL_ * D_ * E_ / 4 + 255) / 256, 256, 0, stream>>>(out_w, out_w_bf, NL_ * D_ * E_ / 4);

    for (int i = 0; i < NL_; ++i) {
        ln_kernel<<<B_ * L_, 256, 0, stream>>>(out, ln_g + i * D_, ln_b + i * D_, xnbf);
        // xz(bf16) = xn @ in_w^T : M=4096, N=2048, K=512
        gemm_mfma<128, 128, 64, 64, 1><<<dim3(32, 16), 256, 0, stream>>>(
            xnbf, D_, in_w_bf + (size_t)i * 2 * E_ * D_, D_, xz, 2 * E_, D_);
        conv_silu<<<(B_ * L_ * E_) / 256, 256, 0, stream>>>(
            xz, cw + i * E_ * 4, cb + i * E_, xcs);
        // dbl(fp32) = xcs @ xp_w^T : M=4096, N=64, K=1024
        gemm_mfma<64, 64, 32, 32, 0><<<dim3(64, 1), 256, 0, stream>>>(
            xcs, E_, xp_w_bf + (size_t)i * G_ * E_, E_, dbl, G_, E_);
        // dt = softplus(dbl[:, :32] @ dt_w^T + dt_b) : M=4096, N=1024, K=32
        gemm_dt<<<dim3(64, 16), 256, 0, stream>>>(
            dbl, G_, dt_w + (size_t)i * E_ * R_, R_, dt, E_, R_, dt_b + i * E_);
        // chunked scan
        scan_pass1<<<B_ * 64 * NC_, 256, 0, stream>>>(
            dt, xcs, dbl, A_log + (size_t)i * E_ * S_, asum, bsum);
        scan_pass2<<<SUM_ / 256, 256, 0, stream>>>(asum, bsum);
        scan_pass3<<<B_ * 64 * NC_, 256, 0, stream>>>(
            dt, xcs, dbl, xz, A_log + (size_t)i * E_ * S_, Dp + i * E_, asum, ybf);
        // out += y @ out_w^T : M=4096, N=512, K=1024
        gemm_mfma<128, 64, 64, 32, 2><<<dim3(32, 8), 256, 0, stream>>>(
            ybf, E_, out_w_bf + (size_t)i * D_ * E_, E_, out, D_, E_);
    }
}

// Round 4
// 757.165 us; speedup vs baseline: 5.9971x; 1.4903x over previous
//
#include <hip/hip_runtime.h>
#include <math.h>

#define B_ 4
#define L_ 1024
#define D_ 512
#define E_ 1024
#define R_ 32
#define S_ 16
#define G_ 64
#define NL_ 4
#define NC_ 32   // chunks over L
#define CT_ 32   // chunk length
#define SUM_ (B_ * E_ * S_)

typedef __attribute__((ext_vector_type(8))) short bf16x8;
typedef __attribute__((ext_vector_type(4))) float f32x4;

__device__ __forceinline__ unsigned short f2bf(float f) {
    unsigned u = __float_as_uint(f);
    u += 0x7fff + ((u >> 16) & 1);   // RNE
    return (unsigned short)(u >> 16);
}
__device__ __forceinline__ float bf2f(unsigned short h) {
    return __uint_as_float((unsigned)h << 16);
}

__device__ __forceinline__ void gload16(const void* g, void* l) {
    __builtin_amdgcn_global_load_lds(
        (const __attribute__((address_space(1))) unsigned int*)g,
        (__attribute__((address_space(3))) unsigned int*)l, 16, 0, 0);
}

// ---------------- copy x -> out (residual stream init) ----------------
__global__ __launch_bounds__(256)
void copy_kernel(const float* __restrict__ src, float* __restrict__ dst, int n4) {
    int i = blockIdx.x * 256 + threadIdx.x;
    if (i < n4) ((float4*)dst)[i] = ((const float4*)src)[i];
}

// ---------------- fp32 -> bf16 bulk convert (weights) ----------------
__global__ __launch_bounds__(256)
void cvt_bf16(const float* __restrict__ src, unsigned short* __restrict__ dst, int n4) {
    int i = blockIdx.x * 256 + threadIdx.x;
    if (i < n4) {
        float4 v = ((const float4*)src)[i];
        ushort4 o;
        o.x = f2bf(v.x); o.y = f2bf(v.y); o.z = f2bf(v.z); o.w = f2bf(v.w);
        ((ushort4*)dst)[i] = o;
    }
}

// ---------------- layernorm over D=512, one block per token, bf16 out ----------------
__global__ __launch_bounds__(256)
void ln_kernel(const float* __restrict__ x, const float* __restrict__ g,
               const float* __restrict__ b, unsigned short* __restrict__ o) {
    int t = blockIdx.x;
    int d = threadIdx.x * 2;
    float2 v = *(const float2*)&x[(size_t)t * D_ + d];
    float s = v.x + v.y;
    float sq = v.x * v.x + v.y * v.y;
#pragma unroll
    for (int m = 1; m < 64; m <<= 1) {
        s += __shfl_xor(s, m);
        sq += __shfl_xor(sq, m);
    }
    __shared__ float ls[4], lq[4];
    int w = threadIdx.x >> 6;
    if ((threadIdx.x & 63) == 0) { ls[w] = s; lq[w] = sq; }
    __syncthreads();
    s = ls[0] + ls[1] + ls[2] + ls[3];
    sq = lq[0] + lq[1] + lq[2] + lq[3];
    float mean = s * (1.0f / D_);
    float var = sq * (1.0f / D_) - mean * mean;
    float rs = rsqrtf(var + 1e-5f);
    float2 gg = *(const float2*)&g[d];
    float2 bb = *(const float2*)&b[d];
    ushort2 r;
    r.x = f2bf((v.x - mean) * rs * gg.x + bb.x);
    r.y = f2bf((v.y - mean) * rs * gg.y + bb.y);
    *(ushort2*)&o[(size_t)t * D_ + d] = r;
}

// ---------------- bf16 MFMA GEMM: C[M,N] = A[M,K] @ W[N,K]^T ----------------
template <int BM, int BN, int WM, int WN, int EPI>
__global__ __launch_bounds__(256)
void gemm_mfma(const unsigned short* __restrict__ A, int lda,
               const unsigned short* __restrict__ W, int ldb,
               void* __restrict__ Cv, int ldc, int K) {
    constexpr int IA = BM / 64;
    constexpr int IB = BN / 64;
    constexpr int NWN = BN / WN;
    constexpr int MI = WM / 16, NJ = WN / 16;
    __shared__ unsigned short As[BM * 32];
    __shared__ unsigned short Bs[BN * 32];
    const int tid = threadIdx.x;
    const int wave = tid >> 6, lane = tid & 63;
    const int quad = lane >> 4, r = lane & 15;
    const int wm = (wave / NWN) * WM, wn = (wave % NWN) * WN;
    const int m0 = blockIdx.x * BM, n0 = blockIdx.y * BN;
    const int arow = tid >> 2, acol = (tid & 3) * 8;
    const unsigned short* Ag = A + (size_t)(m0 + arow) * lda + acol;
    const unsigned short* Wg = W + (size_t)(n0 + arow) * ldb + acol;
    f32x4 acc[MI][NJ] = {};
    for (int k0 = 0; k0 < K; k0 += 32) {
        __syncthreads();
#pragma unroll
        for (int q = 0; q < IA; ++q)
            gload16(Ag + (size_t)(64 * q) * lda + k0, &As[(q * 256 + tid) * 8]);
#pragma unroll
        for (int q = 0; q < IB; ++q)
            gload16(Wg + (size_t)(64 * q) * ldb + k0, &Bs[(q * 256 + tid) * 8]);
        __syncthreads();
        bf16x8 af[MI], bfr[NJ];
#pragma unroll
        for (int i = 0; i < MI; ++i)
            af[i] = *(const bf16x8*)&As[(wm + i * 16 + r) * 32 + quad * 8];
#pragma unroll
        for (int j = 0; j < NJ; ++j)
            bfr[j] = *(const bf16x8*)&Bs[(wn + j * 16 + r) * 32 + quad * 8];
#pragma unroll
        for (int i = 0; i < MI; ++i)
#pragma unroll
            for (int j = 0; j < NJ; ++j)
                acc[i][j] = __builtin_amdgcn_mfma_f32_16x16x32_bf16(af[i], bfr[j], acc[i][j], 0, 0, 0);
    }
#pragma unroll
    for (int i = 0; i < MI; ++i) {
        int mrow = m0 + wm + i * 16 + quad * 4;
#pragma unroll
        for (int j = 0; j < NJ; ++j) {
            int n = n0 + wn + j * 16 + r;
#pragma unroll
            for (int t = 0; t < 4; ++t) {
                float v = acc[i][j][t];
                size_t off = (size_t)(mrow + t) * ldc + n;
                if (EPI == 1) {
                    ((unsigned short*)Cv)[off] = f2bf(v);
                } else if (EPI == 2) {
                    float* C = (float*)Cv;
                    C[off] = v + C[off];
                } else {
                    ((float*)Cv)[off] = v;
                }
            }
        }
    }
}

// ---------------- fp32 vector GEMM (dt_proj only, K=32): softplus epilogue ----------------
__global__ __launch_bounds__(256)
void gemm_dt(const float* __restrict__ A, int lda,
             const float* __restrict__ W, int ldb,
             float* __restrict__ C, int ldc,
             int K, const float* __restrict__ bias) {
    __shared__ float As[64][36];
    __shared__ float Bs[64][36];
    const int tid = threadIdx.x;
    const int tx = tid & 15, ty = tid >> 4;
    const int m0 = blockIdx.x * 64, n0 = blockIdx.y * 64;
    float acc[4][4] = {};
    for (int k0 = 0; k0 < K; k0 += 32) {
#pragma unroll
        for (int i = 0; i < 2; ++i) {
            int q = tid + i * 256;
            int row = q >> 3, kq = (q & 7) * 4;
            *(float4*)&As[row][kq] = *(const float4*)&A[(size_t)(m0 + row) * lda + k0 + kq];
            *(float4*)&Bs[row][kq] = *(const float4*)&W[(size_t)(n0 + row) * ldb + k0 + kq];
        }
        __syncthreads();
#pragma unroll
        for (int k4 = 0; k4 < 8; ++k4) {
            float4 a4[4], b4[4];
#pragma unroll
            for (int u = 0; u < 4; ++u) {
                a4[u] = *(const float4*)&As[ty + 16 * u][k4 * 4];
                b4[u] = *(const float4*)&Bs[tx + 16 * u][k4 * 4];
            }
#pragma unroll
            for (int i = 0; i < 4; ++i)
#pragma unroll
                for (int j = 0; j < 4; ++j) {
                    acc[i][j] = fmaf(a4[i].x, b4[j].x, acc[i][j]);
                    acc[i][j] = fmaf(a4[i].y, b4[j].y, acc[i][j]);
                    acc[i][j] = fmaf(a4[i].z, b4[j].z, acc[i][j]);
                    acc[i][j] = fmaf(a4[i].w, b4[j].w, acc[i][j]);
                }
        }
        __syncthreads();
    }
#pragma unroll
    for (int i = 0; i < 4; ++i) {
        int m = m0 + ty + 16 * i;
#pragma unroll
        for (int j = 0; j < 4; ++j) {
            int n = n0 + tx + 16 * j;
            float v = acc[i][j] + bias[n];
            v = fmaxf(v, 0.f) + log1pf(expf(-fabsf(v)));  // stable softplus
            C[(size_t)m * ldc + n] = v;
        }
    }
}

// ---------------- depthwise causal conv (D_CONV=4) + SiLU, bf16 in/out ----------------
__global__ __launch_bounds__(256)
void conv_silu(const unsigned short* __restrict__ xz, const float* __restrict__ cw,
               const float* __restrict__ cb, unsigned short* __restrict__ xcs) {
    int idx = blockIdx.x * 256 + threadIdx.x;  // over B*L*E
    int d = idx & (E_ - 1);
    int bl = idx >> 10;
    int l = bl & (L_ - 1);
    float4 w = *(const float4*)&cw[d * 4];
    float s = cb[d];
    const unsigned short* p = xz + (size_t)bl * 2 * E_ + d;
    if (l >= 3) s += bf2f(p[-3 * 2 * E_]) * w.x;
    if (l >= 2) s += bf2f(p[-2 * 2 * E_]) * w.y;
    if (l >= 1) s += bf2f(p[-1 * 2 * E_]) * w.z;
    s += bf2f(p[0]) * w.w;
    xcs[idx] = f2bf(s / (1.0f + expf(-s)));
}

// ---------------- chunked selective scan, thread-per-(b,d,chunk) ----------------
// 16 states in registers; B (and C in pass3) staged in LDS, broadcast b128 reads.
__global__ __launch_bounds__(256)
void scan_pass1(const float* __restrict__ dt, const unsigned short* __restrict__ xcs,
                const float* __restrict__ dbl, const float* __restrict__ A_log,
                float* __restrict__ asum, float* __restrict__ bsum) {
    const int tid = threadIdx.x;
    const int dg = blockIdx.x & 3;
    const int c = (blockIdx.x >> 2) & (NC_ - 1);
    const int b = blockIdx.x >> 7;
    const int d = dg * 256 + tid;
    const size_t tb = (size_t)b * L_ + c * CT_;

    __shared__ float BB[CT_][16];
    {
        int trow = tid >> 4, tcol = tid & 15;  // 16 rows per pass, 2 passes
        BB[trow][tcol] = dbl[(tb + trow) * G_ + R_ + tcol];
        BB[16 + trow][tcol] = dbl[(tb + 16 + trow) * G_ + R_ + tcol];
    }
    __syncthreads();

    float A[16];
#pragma unroll
    for (int q = 0; q < 4; ++q) {
        float4 a4 = *(const float4*)&A_log[d * S_ + q * 4];
        A[q * 4 + 0] = -__expf(a4.x);
        A[q * 4 + 1] = -__expf(a4.y);
        A[q * 4 + 2] = -__expf(a4.z);
        A[q * 4 + 3] = -__expf(a4.w);
    }
    float P[16], Q[16];
#pragma unroll
    for (int s = 0; s < 16; ++s) { P[s] = 1.f; Q[s] = 0.f; }

    float dtv = dt[tb * E_ + d];
    float xcv = bf2f(xcs[tb * E_ + d]);
#pragma unroll 2
    for (int l = 0; l < CT_; ++l) {
        int ln = (l + 1 < CT_) ? l + 1 : l;
        float dtn = dt[(tb + ln) * E_ + d];
        float xcn = bf2f(xcs[(tb + ln) * E_ + d]);
        float Bv[16];
#pragma unroll
        for (int q = 0; q < 4; ++q) *(float4*)&Bv[q * 4] = *(const float4*)&BB[l][q * 4];
        float u = dtv * xcv;
#pragma unroll
        for (int s = 0; s < 16; ++s) {
            float dA = __expf(dtv * A[s]);
            P[s] *= dA;
            Q[s] = fmaf(dA, Q[s], u * Bv[s]);
        }
        dtv = dtn; xcv = xcn;
    }
    int base = c * SUM_ + b * (E_ * S_) + d * S_;
#pragma unroll
    for (int q = 0; q < 4; ++q) {
        *(float4*)&asum[base + q * 4] = *(float4*)&P[q * 4];
        *(float4*)&bsum[base + q * 4] = *(float4*)&Q[q * 4];
    }
}

__global__ __launch_bounds__(256)
void scan_pass2(float* __restrict__ asum, const float* __restrict__ bsum) {
    int i = blockIdx.x * 256 + threadIdx.x;
    float h = 0.f;
#pragma unroll
    for (int c = 0; c < NC_; ++c) {
        int idx = c * SUM_ + i;
        float a = asum[idx];
        float q = bsum[idx];
        asum[idx] = h;  // h at chunk entry
        h = fmaf(a, h, q);
    }
}

__global__ __launch_bounds__(256)
void scan_pass3(const float* __restrict__ dt, const unsigned short* __restrict__ xcs,
                const float* __restrict__ dbl, const unsigned short* __restrict__ xzin,
                const float* __restrict__ A_log, const float* __restrict__ Dp,
                const float* __restrict__ h0, unsigned short* __restrict__ ybf) {
    const int tid = threadIdx.x;
    const int dg = blockIdx.x & 3;
    const int c = (blockIdx.x >> 2) & (NC_ - 1);
    const int b = blockIdx.x >> 7;
    const int d = dg * 256 + tid;
    const size_t tb = (size_t)b * L_ + c * CT_;

    __shared__ float BC[CT_][32];
#pragma unroll
    for (int q = 0; q < 4; ++q) {
        int e = q * 256 + tid;
        BC[e >> 5][e & 31] = dbl[(tb + (e >> 5)) * G_ + R_ + (e & 31)];
    }
    __syncthreads();

    float A[16];
#pragma unroll
    for (int q = 0; q < 4; ++q) {
        float4 a4 = *(const float4*)&A_log[d * S_ + q * 4];
        A[q * 4 + 0] = -__expf(a4.x);
        A[q * 4 + 1] = -__expf(a4.y);
        A[q * 4 + 2] = -__expf(a4.z);
        A[q * 4 + 3] = -__expf(a4.w);
    }
    float h[16];
    int base = c * SUM_ + b * (E_ * S_) + d * S_;
#pragma unroll
    for (int q = 0; q < 4; ++q) *(float4*)&h[q * 4] = *(const float4*)&h0[base + q * 4];
    float Dpd = Dp[d];

    float dtv = dt[tb * E_ + d];
    float xcv = bf2f(xcs[tb * E_ + d]);
#pragma unroll 2
    for (int l = 0; l < CT_; ++l) {
        int ln = (l + 1 < CT_) ? l + 1 : l;
        float dtn = dt[(tb + ln) * E_ + d];
        float xcn = bf2f(xcs[(tb + ln) * E_ + d]);
        float Bv[16], Cv[16];
#pragma unroll
        for (int q = 0; q < 4; ++q) {
            *(float4*)&Bv[q * 4] = *(const float4*)&BC[l][q * 4];
            *(float4*)&Cv[q * 4] = *(const float4*)&BC[l][16 + q * 4];
        }
        float u = dtv * xcv;
        float y = 0.f;
#pragma unroll
        for (int s = 0; s < 16; ++s) {
            float dA = __expf(dtv * A[s]);
            h[s] = fmaf(dA, h[s], u * Bv[s]);
            y = fmaf(h[s], Cv[s], y);
        }
        float z = bf2f(xzin[(tb + l) * 2 * E_ + E_ + d]);
        float sz = z / (1.0f + __expf(-z));
        ybf[(tb + l) * E_ + d] = f2bf((y + Dpd * xcv) * sz);
        dtv = dtn; xcv = xcn;
    }
}

extern "C" void kernel_launch(void* const* d_in, const int* in_sizes, int n_in,
                              void* d_out, int out_size, void* d_ws, size_t ws_size,
                              hipStream_t stream) {
    const float* x = (const float*)d_in[0];
    const float* ln_g = (const float*)d_in[1];
    const float* ln_b = (const float*)d_in[2];
    const float* in_w = (const float*)d_in[3];
    const float* cw = (const float*)d_in[4];
    const float* cb = (const float*)d_in[5];
    const float* xp_w = (const float*)d_in[6];
    const float* dt_w = (const float*)d_in[7];
    const float* dt_b = (const float*)d_in[8];
    const float* A_log = (const float*)d_in[9];
    const float* Dp = (const float*)d_in[10];
    const float* out_w = (const float*)d_in[11];
    float* out = (float*)d_out;

    // ---- workspace layout (78 MB) ----
    char* p = (char*)d_ws;
    unsigned short* xz = (unsigned short*)p;        p += (size_t)B_ * L_ * 2 * E_ * 2;
    unsigned short* xcs = (unsigned short*)p;       p += (size_t)B_ * L_ * E_ * 2;
    float* dbl = (float*)p;                         p += (size_t)B_ * L_ * G_ * 4;
    float* dt = (float*)p;                          p += (size_t)B_ * L_ * E_ * 4;
    float* asum = (float*)p;                        p += (size_t)NC_ * SUM_ * 4;
    float* bsum = (float*)p;                        p += (size_t)NC_ * SUM_ * 4;
    unsigned short* ybf = (unsigned short*)p;       // aliased with xnbf (disjoint lifetimes)
    unsigned short* xnbf = (unsigned short*)p;
    p += (size_t)B_ * L_ * E_ * 2;
    unsigned short* in_w_bf = (unsigned short*)p;   p += (size_t)NL_ * 2 * E_ * D_ * 2;
    unsigned short* xp_w_bf = (unsigned short*)p;   p += (size_t)NL_ * G_ * E_ * 2;
    unsigned short* out_w_bf = (unsigned short*)p;

    copy_kernel<<<(B_ * L_ * D_ / 4 + 255) / 256, 256, 0, stream>>>(x, out, B_ * L_ * D_ / 4);
    cvt_bf16<<<(NL_ * 2 * E_ * D_ / 4 + 255) / 256, 256, 0, stream>>>(in_w, in_w_bf, NL_ * 2 * E_ * D_ / 4);
    cvt_bf16<<<(NL_ * G_ * E_ / 4 + 255) / 256, 256, 0, stream>>>(xp_w, xp_w_bf, NL_ * G_ * E_ / 4);
    cvt_bf16<<<(NL_ * D_ * E_ / 4 + 255) / 256, 256, 0, stream>>>(out_w, out_w_bf, NL_ * D_ * E_ / 4);

    for (int i = 0; i < NL_; ++i) {
        ln_kernel<<<B_ * L_, 256, 0, stream>>>(out, ln_g + i * D_, ln_b + i * D_, xnbf);
        gemm_mfma<128, 128, 64, 64, 1><<<dim3(32, 16), 256, 0, stream>>>(
            xnbf, D_, in_w_bf + (size_t)i * 2 * E_ * D_, D_, xz, 2 * E_, D_);
        conv_silu<<<(B_ * L_ * E_) / 256, 256, 0, stream>>>(
            xz, cw + i * E_ * 4, cb + i * E_, xcs);
        gemm_mfma<64, 64, 32, 32, 0><<<dim3(64, 1), 256, 0, stream>>>(
            xcs, E_, xp_w_bf + (size_t)i * G_ * E_, E_, dbl, G_, E_);
        gemm_dt<<<dim3(64, 16), 256, 0, stream>>>(
            dbl, G_, dt_w + (size_t)i * E_ * R_, R_, dt, E_, R_, dt_b + i * E_);
        scan_pass1<<<B_ * NC_ * (E_ / 256), 256, 0, stream>>>(
            dt, xcs, dbl, A_log + (size_t)i * E_ * S_, asum, bsum);
        scan_pass2<<<SUM_ / 256, 256, 0, stream>>>(asum, bsum);
        scan_pass3<<<B_ * NC_ * (E_ / 256), 256, 0, stream>>>(
            dt, xcs, dbl, xz, A_log + (size_t)i * E_ * S_, Dp + i * E_, asum, ybf);
        gemm_mfma<128, 64, 64, 32, 2><<<dim3(32, 8), 256, 0, stream>>>(
            ybf, E_, out_w_bf + (size_t)i * D_ * E_, E_, out, D_, E_);
    }
}